// Round 4
// baseline (69.944 us; speedup 1.0000x reference)
//
#include <hip/hip_runtime.h>
#include <hip/hip_bf16.h>

// Problem constants: B=1, N=1024, T=2048, E=16384, K=32.
#define TT  2048
#define KK  32
#define NN  1024
#define EE  16384
#define CAP 96   // max experts per dst row; Poisson(16) tail beyond 96 is ~1e-40

typedef short short8 __attribute__((ext_vector_type(8)));
typedef float f32x4 __attribute__((ext_vector_type(4)));

__device__ __forceinline__ short f2bf(float f) {
    __hip_bfloat16 h = __float2bfloat16(f);
    return __builtin_bit_cast(short, h);
}

// Prep: x fp32 [N,T] -> bf16 (4 MB, per-XCD-L2 resident for the main kernel).
__global__ __launch_bounds__(256) void xcvt_kernel(const float* __restrict__ x,
                                                   short* __restrict__ xbf) {
    const int i = blockIdx.x * 256 + threadIdx.x;       // 262144 threads, 8 floats each
    const float4* x4 = (const float4*)x;
    const float4 a = x4[2 * i], b = x4[2 * i + 1];
    short8 h;
    h[0] = f2bf(a.x); h[1] = f2bf(a.y); h[2] = f2bf(a.z); h[3] = f2bf(a.w);
    h[4] = f2bf(b.x); h[5] = f2bf(b.y); h[6] = f2bf(b.z); h[7] = f2bf(b.w);
    ((short8*)xbf)[i] = h;
}

// out[n,t] = x[n,t] + sum_{e: dst[e]==n} sum_{m=0..31} kernel[e,m] * x[src[e], t-m]
// One block per row n; 4 waves; wave w processes list entries p%4==w over the full row.
// Per expert, per wave (verified 16x16x32 decomposition from R2):
//   D[r][c] = conv[256s + 16r + c];  A1[r][k]=xh[256s+16r+k-32], B1[k][c]=tap[32+c-k]
//   A2 = A1 shifted +16;            B2[k][c]=tap[16+c-k] for k>=16 else MUST be 0.
// B fragments come from a per-wave LDS table of 8 alignment-shifted copies of the
// reversed zero-padded taps: kt[w][a][pad_a + i] = tap[47-i], pad_a=(a+1)&7, a=c&7.
// Then b1 = ds_read_b128 at s1 = pad_a+15-c+8g (always 8-aligned), b2 at s1+16.
template<bool XBF>
__global__ __launch_bounds__(256, 4) void lti_main_kernel(
    const float* __restrict__ x,     // [N, T] fp32
    const short* __restrict__ xbf,   // [N, T] bf16 (if XBF)
    const float* __restrict__ kern,  // [E, K]
    const int*   __restrict__ src,   // [E]
    const int*   __restrict__ dst,   // [E]
    float*       __restrict__ out)   // [N, T]
{
    const int n   = blockIdx.x;
    const int tid = threadIdx.x;
    const int w   = tid >> 6;     // wave 0..3
    const int ln  = tid & 63;
    const int c   = ln & 15;
    const int g   = ln >> 4;

    __shared__ __align__(16) short xs[4][2080];   // per-wave: [32 halo zeros | 2048 row]
    __shared__ __align__(16) short kt[4][8][72];  // per-wave taps table (8 shifted copies)
    __shared__ __align__(16) float osum[TT];      // row accumulator, init = x[n]
    __shared__ int el_e[CAP];
    __shared__ int el_s[CAP];
    __shared__ int ecount;

    if (tid == 0) ecount = 0;
    if (tid < 128) xs[tid >> 5][tid & 31] = 0;    // causal halos (persist; never overwritten)
    for (int i = tid; i < 4 * 8 * 72; i += 256)   // taps-table zeros (scatter only hits tap slots)
        ((short*)kt)[i] = 0;
    {   // osum = x[n] in fp32 (folds the "+x" into the accumulator)
        const float4* xr = (const float4*)(x + (size_t)n * TT);
        float4* od = (float4*)osum;
        od[tid]       = xr[tid];
        od[tid + 256] = xr[tid + 256];
    }
    // Scan dst once per row (int4, 16 unrolled iters, all in flight).
    const int4* d4 = (const int4*)dst;
    #pragma unroll
    for (int it = 0; it < EE / 1024; ++it) {
        const int i4 = tid + 256 * it;
        const int4 d = d4[i4];
        const int eb = 4 * i4;
        if (d.x == n) { int p = atomicAdd(&ecount, 1); if (p < CAP) { el_e[p] = eb;     el_s[p] = src[eb];     } }
        if (d.y == n) { int p = atomicAdd(&ecount, 1); if (p < CAP) { el_e[p] = eb + 1; el_s[p] = src[eb + 1]; } }
        if (d.z == n) { int p = atomicAdd(&ecount, 1); if (p < CAP) { el_e[p] = eb + 2; el_s[p] = src[eb + 2]; } }
        if (d.w == n) { int p = atomicAdd(&ecount, 1); if (p < CAP) { el_e[p] = eb + 3; el_s[p] = src[eb + 3]; } }
    }
    __syncthreads();
    const int cnt = min(ecount, CAP);

    f32x4 acc[8];
    #pragma unroll
    for (int s = 0; s < 8; ++s) { acc[s][0] = 0.f; acc[s][1] = 0.f; acc[s][2] = 0.f; acc[s][3] = 0.f; }

    const int a_  = c & 7;
    const int pad = (a_ + 1) & 7;
    const int s1  = pad + 15 - c + 8 * g;   // b128-aligned by construction

    short8 row[4]; short tapbf = 0;

    // ---- stage helpers (macros keep everything in registers / program order) ----
    #define LOAD_EXPERT(P)                                                          \
        {                                                                           \
            const int e0 = __builtin_amdgcn_readfirstlane(el_e[P]);                 \
            const int s0 = __builtin_amdgcn_readfirstlane(el_s[P]);                 \
            if (XBF) {                                                              \
                const short8* xr = (const short8*)(xbf + (size_t)s0 * TT);          \
                _Pragma("unroll")                                                   \
                for (int k = 0; k < 4; ++k) row[k] = xr[ln + 64 * k];               \
            } else {                                                                \
                const float4* xr = (const float4*)(x + (size_t)s0 * TT);            \
                _Pragma("unroll")                                                   \
                for (int k = 0; k < 4; ++k) {                                       \
                    const int ci = ln + 64 * k;                                     \
                    float4 u = xr[2 * ci], v = xr[2 * ci + 1];                      \
                    short8 h;                                                       \
                    h[0]=f2bf(u.x); h[1]=f2bf(u.y); h[2]=f2bf(u.z); h[3]=f2bf(u.w); \
                    h[4]=f2bf(v.x); h[5]=f2bf(v.y); h[6]=f2bf(v.z); h[7]=f2bf(v.w); \
                    row[k] = h;                                                     \
                }                                                                   \
            }                                                                       \
            tapbf = 0;                                                              \
            if (ln < KK) tapbf = f2bf(kern[(size_t)e0 * KK + ln]);                  \
        }

    #define COMMIT_EXPERT()                                                         \
        {                                                                           \
            _Pragma("unroll")                                                       \
            for (int k = 0; k < 4; ++k)                                             \
                *(short8*)&xs[w][32 + 8 * (ln + 64 * k)] = row[k];                  \
            if (ln < KK) {                                                          \
                _Pragma("unroll")                                                   \
                for (int a2 = 0; a2 < 8; ++a2)                                      \
                    kt[w][a2][(((a2 + 1) & 7)) + 47 - ln] = tapbf;                  \
            }                                                                       \
        }

    if (w < cnt) {
        LOAD_EXPERT(w);
        COMMIT_EXPERT();
        for (int p = w; p < cnt; p += 4) {
            const bool hn = (p + 4 < cnt);
            if (hn) LOAD_EXPERT(p + 4);          // global loads overlap compute below

            const short8 b1  = *(const short8*)&kt[w][a_][s1];
            const short8 b2r = *(const short8*)&kt[w][a_][s1 + 16];
            short8 z; z[0]=0;z[1]=0;z[2]=0;z[3]=0;z[4]=0;z[5]=0;z[6]=0;z[7]=0;
            const short8 b2 = (g >= 2) ? b2r : z;   // k<16 zeroing is REQUIRED

            #pragma unroll
            for (int s = 0; s < 8; ++s) {
                const short8 a1 = *(const short8*)&xs[w][256 * s + 16 * c + 8 * g];
                const short8 a2 = *(const short8*)&xs[w][256 * s + 16 * c + 8 * g + 16];
                acc[s] = __builtin_amdgcn_mfma_f32_16x16x32_bf16(a1, b1, acc[s], 0, 0, 0);
                acc[s] = __builtin_amdgcn_mfma_f32_16x16x32_bf16(a2, b2, acc[s], 0, 0, 0);
            }

            if (hn) COMMIT_EXPERT();             // after A-reads (in-order within wave)
        }
        // D mapping (verified): col=lane&15, row=4*(lane>>4)+q -> t = 256s+64g+16q+c
        #pragma unroll
        for (int s = 0; s < 8; ++s) {
            #pragma unroll
            for (int q = 0; q < 4; ++q)
                atomicAdd(&osum[256 * s + 64 * g + 16 * q + c], acc[s][q]);
        }
    }
    __syncthreads();

    // Final coalesced store (full overwrite of poisoned d_out).
    float4* ov = (float4*)(out + (size_t)n * TT);
    const float4* os4 = (const float4*)osum;
    ov[tid]       = os4[tid];
    ov[tid + 256] = os4[tid + 256];
    #undef LOAD_EXPERT
    #undef COMMIT_EXPERT
}

extern "C" void kernel_launch(void* const* d_in, const int* in_sizes, int n_in,
                              void* d_out, int out_size, void* d_ws, size_t ws_size,
                              hipStream_t stream) {
    const float* x    = (const float*)d_in[0];
    const float* kern = (const float*)d_in[1];
    const int*   src  = (const int*)d_in[2];
    const int*   dst  = (const int*)d_in[3];
    float*       out  = (float*)d_out;

    const size_t xbf_bytes = (size_t)NN * TT * sizeof(short);
    if (ws_size >= xbf_bytes) {
        short* xbf = (short*)d_ws;
        xcvt_kernel<<<dim3(NN * TT / 8 / 256), dim3(256), 0, stream>>>(x, xbf);
        lti_main_kernel<true><<<dim3(NN), dim3(256), 0, stream>>>(x, xbf, kern, src, dst, out);
    } else {
        lti_main_kernel<false><<<dim3(NN), dim3(256), 0, stream>>>(x, nullptr, kern, src, dst, out);
    }
}

// Round 5
// 50.725 us; speedup vs baseline: 1.3789x; 1.3789x over previous
//
#include <hip/hip_runtime.h>
#include <hip/hip_bf16.h>

// Problem constants: B=1, N=1024, T=2048, E=16384, K=32.
#define TT   2048
#define KK   32
#define NN   1024
#define EE   16384
#define CAP  64    // per-row expert cap (Poisson(16); P(>64) ~ 1e-21)
#define CAPP 64    // per-(wave,partition) cap in scan-fallback mode

typedef short short8 __attribute__((ext_vector_type(8)));
typedef float f32x4 __attribute__((ext_vector_type(4)));

__device__ __forceinline__ short f2bf(float f) {
    __hip_bfloat16 h = __float2bfloat16(f);
    return __builtin_bit_cast(short, h);
}

// Fused prep: out = x (prefill), xbf = bf16(x), and (if CSR) routing table.
// slots[d*CAP+p] packs (src<<14)|e  (e<2^14, src<2^10).
template<bool CSR>
__global__ __launch_bounds__(256) void prep_kernel(
    const float* __restrict__ x, short* __restrict__ xbf, float* __restrict__ out,
    const int* __restrict__ src, const int* __restrict__ dst,
    int* __restrict__ cnt, unsigned* __restrict__ slots)
{
    const int i = blockIdx.x * 256 + threadIdx.x;   // 262144 threads, 8 floats each
    const float4* x4 = (const float4*)x;
    const float4 a = x4[2 * i], b = x4[2 * i + 1];
    float4* o4 = (float4*)out;
    o4[2 * i] = a; o4[2 * i + 1] = b;               // out = x
    short8 hh;
    hh[0] = f2bf(a.x); hh[1] = f2bf(a.y); hh[2] = f2bf(a.z); hh[3] = f2bf(a.w);
    hh[4] = f2bf(b.x); hh[5] = f2bf(b.y); hh[6] = f2bf(b.z); hh[7] = f2bf(b.w);
    ((short8*)xbf)[i] = hh;
    if (CSR && i < EE) {
        const int d = dst[i];
        const int p = atomicAdd(&cnt[d], 1);
        if (p < CAP) slots[(size_t)d * CAP + p] = ((unsigned)src[i] << 14) | (unsigned)i;
    }
}

// Main: one INDEPENDENT wave per (row n, partition j=w, half h). No barriers.
// Verified math (R2/R3): per 256-output segment s, D[r][c]=conv[t0+256s+16r+c]:
//   A1[r][k]=xh[..+k-32] (b128 at xs[256s+16c+8g]), A2 at +16
//   b1 = kt[a][s1..+8), b2 = kt[a][s1+16..+24) with g<2 -> 0 (REQUIRED)
//   kt[a][((a+1)&7) + 47 - m] = tap[m];  a=c&7, s1=((a+1)&7)+15-c+8g (8-aligned)
//   D: col=lane&15, row=4*(lane>>4)+q -> t = t0 + 256s + 64g + 16q + c
// MODE 2: CSR+xbf; 1: xbf + in-wave dst scan; 0: fp32 + in-wave scan.
template<int MODE>
__global__ __launch_bounds__(256, 8) void lti_main(
    const float* __restrict__ x, const short* __restrict__ xbf,
    const float* __restrict__ kern, const int* __restrict__ src,
    const int* __restrict__ dst, const int* __restrict__ cnt,
    const unsigned* __restrict__ slots, float* __restrict__ out)
{
    const int n   = blockIdx.x >> 1;
    const int h   = blockIdx.x & 1;
    const int tid = threadIdx.x;
    const int w   = tid >> 6;        // partition j == w
    const int ln  = tid & 63;
    const int c   = ln & 15, g = ln >> 4;
    const int t0  = 1024 * h;

    __shared__ __align__(16) short xs_all[4][1056];   // per-wave [32 halo | 1024 half-row]
    __shared__ __align__(16) short kt_all[4][8][72];  // per-wave shifted taps table
    __shared__ int wl[4][CAPP];                       // scan-fallback lists
    __shared__ int wc[4];

    short* xs = xs_all[w];
    short (*kt)[72] = kt_all[w];

    short8 z8; z8[0]=0;z8[1]=0;z8[2]=0;z8[3]=0;z8[4]=0;z8[5]=0;z8[6]=0;z8[7]=0;

    // Per-wave init: zero taps table + causal halo (h==0 keeps zeros forever).
    {
        short8* kz = (short8*)&kt[0][0];     // 576 shorts = 72 short8
        kz[ln] = z8;
        if (ln < 8) kz[64 + ln] = z8;
        if (ln < 4) *(short8*)&xs[8 * ln] = z8;
    }

    int L;
    if (MODE == 2) {
        L = cnt[n]; if (L > CAP) L = CAP;
    } else {
        if (ln == 0) wc[w] = 0;
        const int4* d4 = (const int4*)(dst + w * (EE / 4));
        #pragma unroll
        for (int it = 0; it < 16; ++it) {
            const int i4 = ln + 64 * it;
            const int4 d = d4[i4];
            const int eb = w * (EE / 4) + 4 * i4;
            if (d.x == n) { int p = atomicAdd(&wc[w], 1); if (p < CAPP) wl[w][p] = (src[eb    ] << 14) | (eb    ); }
            if (d.y == n) { int p = atomicAdd(&wc[w], 1); if (p < CAPP) wl[w][p] = (src[eb + 1] << 14) | (eb + 1); }
            if (d.z == n) { int p = atomicAdd(&wc[w], 1); if (p < CAPP) wl[w][p] = (src[eb + 2] << 14) | (eb + 2); }
            if (d.w == n) { int p = atomicAdd(&wc[w], 1); if (p < CAPP) wl[w][p] = (src[eb + 3] << 14) | (eb + 3); }
        }
        L = wc[w]; if (L > CAPP) L = CAPP;
    }

    const int pstart = (MODE == 2) ? w : 0;
    const int pstep  = (MODE == 2) ? 4 : 1;

    f32x4 acc0 = {0,0,0,0}, acc1 = {0,0,0,0}, acc2 = {0,0,0,0}, acc3 = {0,0,0,0};
    short8 row0, row1, rowh = z8;
    short tapbf = 0;

    #define FETCH_SLOT(P) ((MODE == 2) ? slots[(size_t)n * CAP + (P)] : (unsigned)wl[w][P])

    #define LOAD_EXPERT(SV)                                                            \
    {                                                                                  \
        const int e0 = __builtin_amdgcn_readfirstlane((int)((SV) & 16383u));           \
        const int s0 = __builtin_amdgcn_readfirstlane((int)((SV) >> 14));              \
        if (MODE >= 1) {                                                               \
            const short8* xr = (const short8*)(xbf + (size_t)s0 * TT + t0);            \
            row0 = xr[ln]; row1 = xr[ln + 64];                                         \
            if (h && ln < 4)                                                           \
                rowh = ((const short8*)(xbf + (size_t)s0 * TT + 992))[ln];             \
        } else {                                                                       \
            const float4* xr = (const float4*)(x + (size_t)s0 * TT + t0);              \
            float4 u = xr[2 * ln], v = xr[2 * ln + 1];                                 \
            row0[0]=f2bf(u.x); row0[1]=f2bf(u.y); row0[2]=f2bf(u.z); row0[3]=f2bf(u.w);\
            row0[4]=f2bf(v.x); row0[5]=f2bf(v.y); row0[6]=f2bf(v.z); row0[7]=f2bf(v.w);\
            u = xr[2 * (ln + 64)]; v = xr[2 * (ln + 64) + 1];                          \
            row1[0]=f2bf(u.x); row1[1]=f2bf(u.y); row1[2]=f2bf(u.z); row1[3]=f2bf(u.w);\
            row1[4]=f2bf(v.x); row1[5]=f2bf(v.y); row1[6]=f2bf(v.z); row1[7]=f2bf(v.w);\
            if (h && ln < 4) {                                                         \
                u = *(const float4*)(x + (size_t)s0 * TT + 992 + 8 * ln);              \
                v = *(const float4*)(x + (size_t)s0 * TT + 996 + 8 * ln);              \
                rowh[0]=f2bf(u.x); rowh[1]=f2bf(u.y); rowh[2]=f2bf(u.z); rowh[3]=f2bf(u.w); \
                rowh[4]=f2bf(v.x); rowh[5]=f2bf(v.y); rowh[6]=f2bf(v.z); rowh[7]=f2bf(v.w); \
            }                                                                          \
        }                                                                              \
        tapbf = 0;                                                                     \
        if (ln < KK) tapbf = f2bf(kern[(size_t)e0 * KK + ln]);                         \
    }

    #define COMMIT_EXPERT()                                                            \
    {                                                                                  \
        *(short8*)&xs[32 + 8 * ln] = row0;                                             \
        *(short8*)&xs[32 + 8 * (ln + 64)] = row1;                                      \
        if (h && ln < 4) *(short8*)&xs[8 * ln] = rowh;                                 \
        if (ln < KK) {                                                                 \
            _Pragma("unroll")                                                          \
            for (int a2 = 0; a2 < 8; ++a2)                                             \
                kt[a2][((a2 + 1) & 7) + 47 - ln] = tapbf;                              \
        }                                                                              \
    }

    const int a_ = c & 7;
    const int s1 = ((a_ + 1) & 7) + 15 - c + 8 * g;   // b128-aligned by construction

    if (pstart < L) {
        unsigned sv = FETCH_SLOT(pstart);
        LOAD_EXPERT(sv);
        for (int p = pstart; p < L; p += pstep) {
            COMMIT_EXPERT();
            const bool hn = (p + pstep < L);
            if (hn) { unsigned svn = FETCH_SLOT(p + pstep); LOAD_EXPERT(svn); }

            const short8 b1 = *(const short8*)&kt[a_][s1];
            short8 b2 = *(const short8*)&kt[a_][s1 + 16];
            if (g < 2) b2 = z8;   // k<16 zeroing is REQUIRED

            #pragma unroll
            for (int s = 0; s < 4; ++s) {
                const short8 a1  = *(const short8*)&xs[256 * s + 16 * c + 8 * g];
                const short8 a2v = *(const short8*)&xs[256 * s + 16 * c + 8 * g + 16];
                f32x4& ac = (s == 0) ? acc0 : (s == 1) ? acc1 : (s == 2) ? acc2 : acc3;
                ac = __builtin_amdgcn_mfma_f32_16x16x32_bf16(a1,  b1, ac, 0, 0, 0);
                ac = __builtin_amdgcn_mfma_f32_16x16x32_bf16(a2v, b2, ac, 0, 0, 0);
            }
        }
        // Scatter-add partition contribution (out prefilled with x).
        float* orow = out + (size_t)n * TT + t0;
        #pragma unroll
        for (int s = 0; s < 4; ++s) {
            const f32x4 ac = (s == 0) ? acc0 : (s == 1) ? acc1 : (s == 2) ? acc2 : acc3;
            #pragma unroll
            for (int q = 0; q < 4; ++q)
                atomicAdd(orow + 256 * s + 64 * g + 16 * q + c, ac[q]);
        }
    }
    #undef FETCH_SLOT
    #undef LOAD_EXPERT
    #undef COMMIT_EXPERT
}

extern "C" void kernel_launch(void* const* d_in, const int* in_sizes, int n_in,
                              void* d_out, int out_size, void* d_ws, size_t ws_size,
                              hipStream_t stream) {
    const float* x    = (const float*)d_in[0];
    const float* kern = (const float*)d_in[1];
    const int*   src  = (const int*)d_in[2];
    const int*   dst  = (const int*)d_in[3];
    float*       out  = (float*)d_out;

    const size_t CNT_B  = (size_t)NN * 4;                 // 4 KB
    const size_t SLOT_B = (size_t)NN * CAP * 4;           // 256 KB
    const size_t XBF_B  = (size_t)NN * TT * 2;            // 4 MB
    char* wsb = (char*)d_ws;
    int*      cnt   = (int*)wsb;
    unsigned* slots = (unsigned*)(wsb + CNT_B);
    short*    xbf   = (short*)(wsb + CNT_B + SLOT_B);

    if (ws_size >= CNT_B + SLOT_B + XBF_B) {
        hipMemsetAsync(cnt, 0, CNT_B, stream);
        prep_kernel<true><<<dim3(NN * TT / 8 / 256), dim3(256), 0, stream>>>(
            x, xbf, out, src, dst, cnt, slots);
        lti_main<2><<<dim3(NN * 2), dim3(256), 0, stream>>>(
            x, xbf, kern, src, dst, cnt, slots, out);
    } else if (ws_size >= XBF_B) {
        short* xbf2 = (short*)wsb;
        prep_kernel<false><<<dim3(NN * TT / 8 / 256), dim3(256), 0, stream>>>(
            x, xbf2, out, src, dst, nullptr, nullptr);
        lti_main<1><<<dim3(NN * 2), dim3(256), 0, stream>>>(
            x, xbf2, kern, src, dst, nullptr, nullptr, out);
    } else {
        hipMemcpyAsync(out, x, sizeof(float) * (size_t)NN * TT,
                       hipMemcpyDeviceToDevice, stream);
        lti_main<0><<<dim3(NN * 2), dim3(256), 0, stream>>>(
            x, nullptr, kern, src, dst, nullptr, nullptr, out);
    }
}

// Round 6
// 40.129 us; speedup vs baseline: 1.7430x; 1.2641x over previous
//
#include <hip/hip_runtime.h>
#include <hip/hip_bf16.h>

// Problem constants: B=1, N=1024, T=2048, E=16384, K=32.
#define TT  2048
#define KK  32
#define NN  1024
#define EE  16384
#define CAP 64   // per-row expert cap (Poisson(16); P(>64) ~ 1e-21)

typedef short short8 __attribute__((ext_vector_type(8)));
typedef float f32x4 __attribute__((ext_vector_type(4)));

__device__ __forceinline__ short f2bf(float f) {
    __hip_bfloat16 h = __float2bfloat16(f);
    return __builtin_bit_cast(short, h);
}

// Zero the CSR counters (replaces hipMemsetAsync — fill node was 42us in-graph).
__global__ __launch_bounds__(256) void zero_cnt_kernel(int* __restrict__ cnt) {
    const int i = blockIdx.x * 256 + threadIdx.x;
    if (i < NN) cnt[i] = 0;
}

// Prep: xbf = bf16(x) and (if CSR) routing table. slots packs (src<<14)|e.
template<bool CSR>
__global__ __launch_bounds__(256) void prep_kernel(
    const float* __restrict__ x, short* __restrict__ xbf,
    const int* __restrict__ src, const int* __restrict__ dst,
    int* __restrict__ cnt, unsigned* __restrict__ slots)
{
    const int i = blockIdx.x * 256 + threadIdx.x;   // 262144 threads, 8 floats each
    const float4* x4 = (const float4*)x;
    const float4 a = x4[2 * i], b = x4[2 * i + 1];
    short8 hh;
    hh[0] = f2bf(a.x); hh[1] = f2bf(a.y); hh[2] = f2bf(a.z); hh[3] = f2bf(a.w);
    hh[4] = f2bf(b.x); hh[5] = f2bf(b.y); hh[6] = f2bf(b.z); hh[7] = f2bf(b.w);
    ((short8*)xbf)[i] = hh;
    if (CSR && i < EE) {
        const int d = dst[i];
        const int p = atomicAdd(&cnt[d], 1);
        if (p < CAP) slots[(size_t)d * CAP + p] = ((unsigned)src[i] << 14) | (unsigned)i;
    }
}

// Main: one INDEPENDENT wave per (row n, 512-wide t-slice w). Wave processes ALL
// experts of its row but only its slice -> exclusively owns 512 outputs -> plain
// stores, ZERO atomics, no barriers (MODE 2).
// Verified math (R2-R4): per 256-output segment s in the slice,
//   A1 b128 at xs[256s+16c+8g], A2 at +16 (xs = [32-halo | 512 slice] bf16)
//   b1 = kt[a][s1..+8), b2 = kt[a][s1+16..+24) with g<2 -> 0 (REQUIRED)
//   kt[a][((a+1)&7)+47-m] = tap[m];  a = c&7, s1 = ((a+1)&7)+15-c+8g (8-aligned)
//   D: col=c=lane&15, row=4g+q -> t = 512w + 256s + 64g + 16q + c
// MODE 2: CSR+xbf; 1: xbf + block-coop dst scan; 0: fp32 + block-coop scan.
template<int MODE>
__global__ __launch_bounds__(256, 8) void lti_main(
    const float* __restrict__ x, const short* __restrict__ xbf,
    const float* __restrict__ kern, const int* __restrict__ src,
    const int* __restrict__ dst, const int* __restrict__ cnt,
    const unsigned* __restrict__ slots, float* __restrict__ out)
{
    const int n   = blockIdx.x;
    const int tid = threadIdx.x;
    const int w   = tid >> 6;        // t-slice index, 0..3
    const int ln  = tid & 63;
    const int c   = ln & 15, g = ln >> 4;
    const int t0  = 512 * w;

    __shared__ __align__(16) short xs_all[4][544];    // per-wave [32 halo | 512 slice]
    __shared__ __align__(16) short kt_all[4][8][72];  // per-wave shifted taps table
    __shared__ int bl[CAP];                           // fallback scan list
    __shared__ int bc;

    short* xs = xs_all[w];
    short (*kt)[72] = kt_all[w];

    short8 z8; z8[0]=0;z8[1]=0;z8[2]=0;z8[3]=0;z8[4]=0;z8[5]=0;z8[6]=0;z8[7]=0;

    // Per-wave init: zero taps table; wave 0 zeroes its causal halo (persists).
    {
        short8* kz = (short8*)&kt[0][0];   // 576 shorts = 72 short8
        kz[ln] = z8;
        if (ln < 8) kz[64 + ln] = z8;
        if (w == 0 && ln < 4) *(short8*)&xs[8 * ln] = z8;
    }

    int L;
    if (MODE == 2) {
        L = cnt[n]; if (L > CAP) L = CAP;
    } else {
        if (tid == 0) bc = 0;
        __syncthreads();
        const int4* d4 = (const int4*)dst;
        #pragma unroll
        for (int it = 0; it < EE / 1024; ++it) {
            const int i4 = tid + 256 * it;
            const int4 d = d4[i4];
            const int eb = 4 * i4;
            if (d.x == n) { int p = atomicAdd(&bc, 1); if (p < CAP) bl[p] = (src[eb    ] << 14) | (eb    ); }
            if (d.y == n) { int p = atomicAdd(&bc, 1); if (p < CAP) bl[p] = (src[eb + 1] << 14) | (eb + 1); }
            if (d.z == n) { int p = atomicAdd(&bc, 1); if (p < CAP) bl[p] = (src[eb + 2] << 14) | (eb + 2); }
            if (d.w == n) { int p = atomicAdd(&bc, 1); if (p < CAP) bl[p] = (src[eb + 3] << 14) | (eb + 3); }
        }
        __syncthreads();
        L = bc; if (L > CAP) L = CAP;
    }

    f32x4 acc0 = {0,0,0,0}, acc1 = {0,0,0,0};
    short8 row0, rowh = z8;
    short tapbf = 0;

    #define FETCH_SLOT(P) ((MODE == 2) ? slots[(size_t)n * CAP + (P)] : (unsigned)bl[P])

    #define LOAD_EXPERT(SV)                                                            \
    {                                                                                  \
        const int e0 = __builtin_amdgcn_readfirstlane((int)((SV) & 16383u));           \
        const int s0 = __builtin_amdgcn_readfirstlane((int)((SV) >> 14));              \
        if (MODE >= 1) {                                                               \
            row0 = *(const short8*)(xbf + (size_t)s0 * TT + t0 + 8 * ln);              \
            if (w && ln < 4)                                                           \
                rowh = *(const short8*)(xbf + (size_t)s0 * TT + t0 - 32 + 8 * ln);     \
        } else {                                                                       \
            const float4* xr = (const float4*)(x + (size_t)s0 * TT + t0);              \
            float4 u = xr[2 * ln], v = xr[2 * ln + 1];                                 \
            row0[0]=f2bf(u.x); row0[1]=f2bf(u.y); row0[2]=f2bf(u.z); row0[3]=f2bf(u.w);\
            row0[4]=f2bf(v.x); row0[5]=f2bf(v.y); row0[6]=f2bf(v.z); row0[7]=f2bf(v.w);\
            if (w && ln < 4) {                                                         \
                u = *(const float4*)(x + (size_t)s0 * TT + t0 - 32 + 8 * ln);          \
                v = *(const float4*)(x + (size_t)s0 * TT + t0 - 28 + 8 * ln);          \
                rowh[0]=f2bf(u.x); rowh[1]=f2bf(u.y); rowh[2]=f2bf(u.z); rowh[3]=f2bf(u.w); \
                rowh[4]=f2bf(v.x); rowh[5]=f2bf(v.y); rowh[6]=f2bf(v.z); rowh[7]=f2bf(v.w); \
            }                                                                          \
        }                                                                              \
        tapbf = 0;                                                                     \
        if (ln < KK) tapbf = f2bf(kern[(size_t)e0 * KK + ln]);                         \
    }

    #define COMMIT_EXPERT()                                                            \
    {                                                                                  \
        *(short8*)&xs[32 + 8 * ln] = row0;                                             \
        if (w && ln < 4) *(short8*)&xs[8 * ln] = rowh;                                 \
        if (ln < KK) {                                                                 \
            _Pragma("unroll")                                                          \
            for (int a2 = 0; a2 < 8; ++a2)                                             \
                kt[a2][((a2 + 1) & 7) + 47 - ln] = tapbf;                              \
        }                                                                              \
    }

    const int a_ = c & 7;
    const int s1 = ((a_ + 1) & 7) + 15 - c + 8 * g;   // b128-aligned by construction

    if (L > 0) {
        unsigned sv = FETCH_SLOT(0);
        LOAD_EXPERT(sv);
        for (int p = 0; p < L; ++p) {
            COMMIT_EXPERT();
            const bool hn = (p + 1 < L);
            if (hn) { unsigned svn = FETCH_SLOT(p + 1); LOAD_EXPERT(svn); }

            const short8 b1 = *(const short8*)&kt[a_][s1];
            short8 b2 = *(const short8*)&kt[a_][s1 + 16];
            if (g < 2) b2 = z8;   // k<16 zeroing is REQUIRED

            {
                const short8 a1  = *(const short8*)&xs[16 * c + 8 * g];
                const short8 a2v = *(const short8*)&xs[16 * c + 8 * g + 16];
                acc0 = __builtin_amdgcn_mfma_f32_16x16x32_bf16(a1,  b1, acc0, 0, 0, 0);
                acc0 = __builtin_amdgcn_mfma_f32_16x16x32_bf16(a2v, b2, acc0, 0, 0, 0);
            }
            {
                const short8 a1  = *(const short8*)&xs[256 + 16 * c + 8 * g];
                const short8 a2v = *(const short8*)&xs[256 + 16 * c + 8 * g + 16];
                acc1 = __builtin_amdgcn_mfma_f32_16x16x32_bf16(a1,  b1, acc1, 0, 0, 0);
                acc1 = __builtin_amdgcn_mfma_f32_16x16x32_bf16(a2v, b2, acc1, 0, 0, 0);
            }
        }
    }

    // Epilogue: this wave owns out[n, t0 .. t0+512) exclusively -> plain stores.
    // t = 256s + 64g + 16q + c (wave-relative); lanes c=0..15 are contiguous.
    const float* xr  = x   + (size_t)n * TT + t0;
    float*       orw = out + (size_t)n * TT + t0;
    #pragma unroll
    for (int q = 0; q < 4; ++q) {
        const int ta = 64 * g + 16 * q + c;
        orw[ta]       = xr[ta]       + acc0[q];
        orw[256 + ta] = xr[256 + ta] + acc1[q];
    }
    #undef FETCH_SLOT
    #undef LOAD_EXPERT
    #undef COMMIT_EXPERT
}

extern "C" void kernel_launch(void* const* d_in, const int* in_sizes, int n_in,
                              void* d_out, int out_size, void* d_ws, size_t ws_size,
                              hipStream_t stream) {
    const float* x    = (const float*)d_in[0];
    const float* kern = (const float*)d_in[1];
    const int*   src  = (const int*)d_in[2];
    const int*   dst  = (const int*)d_in[3];
    float*       out  = (float*)d_out;

    const size_t CNT_B  = (size_t)NN * 4;        // 4 KB
    const size_t SLOT_B = (size_t)NN * CAP * 4;  // 256 KB
    const size_t XBF_B  = (size_t)NN * TT * 2;   // 4 MB
    char* wsb = (char*)d_ws;
    int*      cnt   = (int*)wsb;
    unsigned* slots = (unsigned*)(wsb + CNT_B);
    short*    xbf   = (short*)(wsb + CNT_B + SLOT_B);

    if (ws_size >= CNT_B + SLOT_B + XBF_B) {
        zero_cnt_kernel<<<dim3(4), dim3(256), 0, stream>>>(cnt);
        prep_kernel<true><<<dim3(NN * TT / 8 / 256), dim3(256), 0, stream>>>(
            x, xbf, src, dst, cnt, slots);
        lti_main<2><<<dim3(NN), dim3(256), 0, stream>>>(
            x, xbf, kern, src, dst, cnt, slots, out);
    } else if (ws_size >= XBF_B) {
        short* xbf2 = (short*)wsb;
        prep_kernel<false><<<dim3(NN * TT / 8 / 256), dim3(256), 0, stream>>>(
            x, xbf2, src, dst, nullptr, nullptr);
        lti_main<1><<<dim3(NN), dim3(256), 0, stream>>>(
            x, xbf2, kern, src, dst, nullptr, nullptr, out);
    } else {
        lti_main<0><<<dim3(NN), dim3(256), 0, stream>>>(
            x, nullptr, kern, src, dst, nullptr, nullptr, out);
    }
}